// Round 7
// baseline (463.614 us; speedup 1.0000x reference)
//
#include <hip/hip_runtime.h>
#include <math.h>

// Problem constants (fixed by reference)
#define BATCH 4096
#define LNUM  4
#define NEIGH 32
#define FEAT  256
#define EMB   128
#define NODES 100000

#define NPASS 32
#define SLICE (NODES / NPASS)  // 3125 nodes = 3.2 MB fp32: fits 4 MiB XCD-L2

// ---------------------------------------------------------------------------
// K12: L2-SLICED gather+sum + h-GEMM for 32 batches x 1 layer. Grid (128, 4).
// P1: neighbor rows are gathered in 32 node-range passes; each pass touches a
// 3.2 MB slice of the feature table so concurrent blocks on one XCD hit L2
// (~200 cyc) instead of LLC/HBM (~600+ cyc) -> ~3x request throughput under
// the per-CU outstanding-line cap (R2/R4/R5/R6 falsified width/count/wave
// scaling; latency class is the only remaining factor).
// Row accumulators live in VGPRs across passes (float4/lane x 8 rows).
// P2: W[l] staged through LDS once per block (64 MB total W traffic).
// LDS: sS 33.3 KB + sW 16 KB -> 2 blocks/CU (grid 512 = 2/CU resident).
// ---------------------------------------------------------------------------
__global__ __launch_bounds__(256, 2) void k12(
    const int* __restrict__ neighs, const float* __restrict__ features,
    const float* __restrict__ W, float* __restrict__ H) {
  __shared__ float sS[32][260];
  __shared__ float sW[32][128];
  int b0 = blockIdx.x * 32;
  int l = blockIdx.y;
  int tid = threadIdx.x;
  int w = tid >> 6, lane = tid & 63;

  // ---- P1: wave w owns rows w*8 .. w*8+7 --------------------------------
  int idx[8];
#pragma unroll
  for (int i = 0; i < 8; ++i) {
    const int* nbr = neighs + ((size_t)(b0 + w * 8 + i) * LNUM + l) * NEIGH;
    idx[i] = nbr[lane & 31];  // lanes 0..31 hold the 32 indices (dup hi half)
  }
  float4 acc[8];
#pragma unroll
  for (int i = 0; i < 8; ++i) acc[i] = make_float4(0.f, 0.f, 0.f, 0.f);

  for (int p = 0; p < NPASS; ++p) {
    int lo = p * SLICE;
#pragma unroll
    for (int i = 0; i < 8; ++i) {
      // which of this row's 32 neighbors fall in the current slice?
      bool inr = ((unsigned int)(idx[i] - lo)) < (unsigned int)SLICE;
      unsigned long long m = __ballot(inr) & 0xffffffffull;
      while (m) {
        int j = __ffsll((long long)m) - 1;
        m &= m - 1;
        int n = __shfl(idx[i], j, 64);  // uniform row id within slice
        float4 v = *((const float4*)(features + (size_t)n * FEAT) + lane);
        acc[i].x += v.x; acc[i].y += v.y;
        acc[i].z += v.z; acc[i].w += v.w;
      }
    }
  }
#pragma unroll
  for (int i = 0; i < 8; ++i)
    *(float4*)&sS[w * 8 + i][lane * 4] = acc[i];
  __syncthreads();

  // ---- P2: H rows = sS rows @ W[l]; W staged through LDS once per block.
  int tx = tid & 31;   // cols tx*4..+3
  int ty = tid >> 5;   // rows ty*4..+3
  float accO[4][4] = {};
  const float* Wl = W + (size_t)l * FEAT * EMB;
  for (int k0 = 0; k0 < FEAT; k0 += 32) {
#pragma unroll
    for (int t = 0; t < 4; ++t) {   // stage 32x128 chunk (16 KB)
      int i2 = tid + t * 256;       // float4 index 0..1023
      int kk = i2 >> 5;
      int cc = i2 & 31;
      *(float4*)&sW[kk][cc * 4] =
          *(const float4*)&Wl[(size_t)(k0 + kk) * EMB + cc * 4];
    }
    __syncthreads();
#pragma unroll
    for (int kc = 0; kc < 32; kc += 4) {
      float4 s4[4];
#pragma unroll
      for (int r = 0; r < 4; ++r)
        s4[r] = *(const float4*)&sS[ty * 4 + r][k0 + kc];
#pragma unroll
      for (int kk = 0; kk < 4; ++kk) {
        float4 wv = *(const float4*)&sW[kc + kk][tx * 4];
#pragma unroll
        for (int r = 0; r < 4; ++r) {
          float sv = ((const float*)&s4[r])[kk];
          accO[r][0] += sv * wv.x; accO[r][1] += sv * wv.y;
          accO[r][2] += sv * wv.z; accO[r][3] += sv * wv.w;
        }
      }
    }
    __syncthreads();
  }
#pragma unroll
  for (int r = 0; r < 4; ++r) {
    int b = b0 + ty * 4 + r;
    *(float4*)&H[((size_t)b * LNUM + l) * EMB + tx * 4] =
        make_float4(accO[r][0], accO[r][1], accO[r][2], accO[r][3]);
  }
}

// ---------------------------------------------------------------------------
// K34: scores + softmax + agg + out-GEMM + residual + L2-normalize for
// 16 batches (64 (b,l) rows) per block. Grid 256 x 256 threads.
// ---------------------------------------------------------------------------
__global__ __launch_bounds__(256, 2) void k34(
    const float* __restrict__ H, const float* __restrict__ Ws1,
    const float* __restrict__ Ws2, const float* __restrict__ Wt,
    const int* __restrict__ node_i, const int* __restrict__ layers,
    const float* __restrict__ layer_embs, float* __restrict__ out) {
  __shared__ float sHH[64][130];
  __shared__ float sAgg[16][128];
  __shared__ float sc[64];
  int b0 = blockIdx.x * 16;
  int tid = threadIdx.x;
  int w = tid >> 6, lane = tid & 63;

  {
    const float4* Hp = (const float4*)(H + (size_t)b0 * LNUM * EMB);
    for (int i = tid; i < 64 * 32; i += 256) {
      int r = i >> 5, c = i & 31;
      *(float4*)&sHH[r][c * 4] = Hp[i];
    }
  }
  __syncthreads();

  // ---- P3: sc[r] = tanh(sHH[r] @ Ws1) @ Ws2; wave w rows w*16..w*16+15
  {
    float acc[16][2] = {};
    for (int k = 0; k < EMB; k += 2) {
      float2 h2[16];
#pragma unroll
      for (int r = 0; r < 16; ++r)
        h2[r] = *(const float2*)&sHH[w * 16 + r][k];  // wave-uniform: bcast
      float2 w0 = *(const float2*)&Ws1[(size_t)k * EMB + lane * 2];
      float2 w1 = *(const float2*)&Ws1[(size_t)(k + 1) * EMB + lane * 2];
#pragma unroll
      for (int r = 0; r < 16; ++r) {
        acc[r][0] += h2[r].x * w0.x + h2[r].y * w1.x;
        acc[r][1] += h2[r].x * w0.y + h2[r].y * w1.y;
      }
    }
    float2 w2v = *(const float2*)&Ws2[lane * 2];
#pragma unroll
    for (int r = 0; r < 16; ++r) {
      float p = tanhf(acc[r][0]) * w2v.x + tanhf(acc[r][1]) * w2v.y;
#pragma unroll
      for (int m = 1; m < 64; m <<= 1) p += __shfl_xor(p, m, 64);
      if (lane == 0) sc[w * 16 + r] = p;
    }
  }
  __syncthreads();

  // ---- P4a: softmax over layers + attention-weighted aggregation
  for (int i = tid; i < 16 * EMB; i += 256) {
    int lb = i >> 7, m = i & 127;
    float s0 = sc[lb * 4 + 0], s1 = sc[lb * 4 + 1];
    float s2 = sc[lb * 4 + 2], s3 = sc[lb * 4 + 3];
    float mx = fmaxf(fmaxf(s0, s1), fmaxf(s2, s3));
    float e0 = expf(s0 - mx), e1 = expf(s1 - mx);
    float e2 = expf(s2 - mx), e3 = expf(s3 - mx);
    float inv = 1.0f / (e0 + e1 + e2 + e3);
    float a = e0 * sHH[lb * 4 + 0][m] + e1 * sHH[lb * 4 + 1][m] +
              e2 * sHH[lb * 4 + 2][m] + e3 * sHH[lb * 4 + 3][m];
    sAgg[lb][m] = a * inv;
  }
  __syncthreads();

  // ---- P4b: wave w -> local batches w*4..w*4+3; Wt read once per wave
  {
    float ax[4] = {0.f, 0.f, 0.f, 0.f}, ay[4] = {0.f, 0.f, 0.f, 0.f};
    for (int k = 0; k < EMB; ++k) {
      float2 wv = *(const float2*)&Wt[(size_t)k * EMB + lane * 2];
#pragma unroll
      for (int g = 0; g < 4; ++g) {
        float a = sAgg[w * 4 + g][k];  // wave-uniform: bcast
        ax[g] += a * wv.x;
        ay[g] += a * wv.y;
      }
    }
#pragma unroll
    for (int g = 0; g < 4; ++g) {
      int b = b0 + w * 4 + g;
      int node = node_i[b];
      int lay = layers[b];
      float2 e = *(const float2*)&layer_embs[((size_t)node * LNUM + lay) * EMB +
                                             lane * 2];
      float vx = ax[g] + e.x, vy = ay[g] + e.y;
      float ss = vx * vx + vy * vy;
#pragma unroll
      for (int m = 1; m < 64; m <<= 1) ss += __shfl_xor(ss, m, 64);
      float inv = 1.0f / fmaxf(sqrtf(ss), 1e-12f);
      *(float2*)&out[(size_t)b * EMB + lane * 2] =
          make_float2(vx * inv, vy * inv);
    }
  }
}

extern "C" void kernel_launch(void* const* d_in, const int* in_sizes, int n_in,
                              void* d_out, int out_size, void* d_ws,
                              size_t ws_size, hipStream_t stream) {
  const int* layers = (const int*)d_in[0];
  const int* node_i = (const int*)d_in[1];
  const int* neighs = (const int*)d_in[2];
  const float* features = (const float*)d_in[3];
  const float* layer_embs = (const float*)d_in[4];
  const float* neigh_emb_trans = (const float*)d_in[5];
  const float* trans_weights = (const float*)d_in[6];
  const float* trans_weights_s1 = (const float*)d_in[7];
  const float* trans_weights_s2 = (const float*)d_in[8];
  float* out = (float*)d_out;

  // ws layout: H (16384x128 fp32, 8.4 MB)
  float* H = (float*)d_ws;

  k12<<<dim3(BATCH / 32, LNUM), 256, 0, stream>>>(neighs, features,
                                                  neigh_emb_trans, H);
  k34<<<dim3(BATCH / 16), 256, 0, stream>>>(H, trans_weights_s1,
                                            trans_weights_s2, trans_weights,
                                            node_i, layers, layer_embs, out);
}